// Round 15
// baseline (373.881 us; speedup 1.0000x reference)
//
#include <hip/hip_runtime.h>
#include <hip/hip_bf16.h>
#include <hip/hip_cooperative_groups.h>

namespace cg = cooperative_groups;

#define D 128
#define NH 4
#define NEG_SLOPE 0.2f
#define LN_EPS 1e-5f

typedef __attribute__((ext_vector_type(4))) float f32x4;
typedef __attribute__((ext_vector_type(8))) short bf16x8;

__device__ __forceinline__ float bf2f(unsigned short u) {
  union { unsigned int i; float f; } c; c.i = ((unsigned int)u) << 16; return c.f;
}
__device__ __forceinline__ unsigned short f2bf(float f) {
  union { float f; unsigned int i; } c; c.f = f;
  unsigned int r = c.i + 0x7FFFu + ((c.i >> 16) & 1u);  // RNE
  return (unsigned short)(r >> 16);
}

// ---------------- weight prep + deg zeroing -------------------------------------
__global__ __launch_bounds__(128) void k_prep(
    const float* __restrict__ Wgat, const float* __restrict__ Wgcn,
    const float* __restrict__ att_src, const float* __restrict__ att_dst,
    unsigned short* __restrict__ Wt2g, unsigned short* __restrict__ Wt2c,
    float* __restrict__ wtil_s, float* __restrict__ wtil_d,
    int* __restrict__ deg, int N)
{
  int c = blockIdx.x, t = threadIdx.x;
  if (c < 128) {
    #pragma unroll
    for (int i = 0; i < 4; ++i) {
      int k = t + i * 128;
      int h = k >> 7, kk = k & 127;
      Wt2g[c * 512 + k] = f2bf(Wgat[((size_t)h * D + kk) * D + c]);
    }
  } else if (c < 256) {
    int cc = c - 128;
    Wt2c[cc * 128 + t] = f2bf(Wgcn[(size_t)t * D + cc]);
  } else if (c < 264) {
    int b2 = c - 256;
    int h = b2 >> 1, which = b2 & 1;
    const float* av = (which ? att_dst : att_src) + h * D;
    const float* Wrow = Wgat + ((size_t)h * D + t) * D;
    float s = 0.f;
    for (int f = 0; f < D; ++f) s += Wrow[f] * av[f];
    (which ? wtil_d : wtil_s)[h * D + t] = s;
  } else {
    int i = (c - 264) * 128 + t;
    if (i < N) deg[i] = 0;
  }
}

// ---------------- agg accumulate macro ------------------------------------------
#define ACC_EDGE(AL, CF, XV) do {                                        \
    float fa_[4] = {bf2f(XV.x), bf2f(XV.y), bf2f(XV.z), bf2f(XV.w)};     \
    float aa_[4] = {AL.x, AL.y, AL.z, AL.w};                             \
    _Pragma("unroll") for (int h_ = 0; h_ < 4; ++h_)                     \
      _Pragma("unroll") for (int d_ = 0; d_ < 4; ++d_)                   \
        ug[h_][d_] += aa_[h_] * fa_[d_];                                 \
    _Pragma("unroll") for (int d_ = 0; d_ < 4; ++d_)                     \
      vg[d_] += (CF) * fa_[d_];                                          \
  } while (0)

// ================== cooperative mega kernel =====================================
// phases: 1) node xb+att / edge deg  2) scan1  3) scan3  4) fill  5) agg2
__global__ __launch_bounds__(256, 4) void k_mega(
    const float* __restrict__ x,
    const float* __restrict__ wtil_s, const float* __restrict__ wtil_d,
    unsigned short* __restrict__ xb, float* __restrict__ a_s, float* __restrict__ a_d,
    const int* __restrict__ ei, int* __restrict__ deg, int* __restrict__ bsum,
    int* __restrict__ row_ptr, int* __restrict__ cursor, float* __restrict__ dinv,
    int* __restrict__ col_src, unsigned short* __restrict__ UV,
    int N, int E, int Et, int NBN, int NBE, int nb, int NG)
{
  cg::grid_group grid = cg::this_grid();
  const int t = threadIdx.x;
  const int nblk = gridDim.x;

  __shared__ int sA[256];
  __shared__ int sB[256];
  __shared__ float4 sh_al[8][40];
  __shared__ int    sh_src[8][40];
  __shared__ float  sh_cf[8][40];

  // ---- phase 1a: node xb + attention dots ----
  for (int vb = blockIdx.x; vb < NBN; vb += nblk) {
    const int w = t >> 6, l = t & 63;
    const int n = vb * 4 + w;
    if (n < N) {
      float2 xv = ((const float2*)(x + (size_t)n * D))[l];
      ushort2 p2; p2.x = f2bf(xv.x); p2.y = f2bf(xv.y);
      *(ushort2*)(xb + (size_t)n * D + 2 * l) = p2;
      float s0 = xv.x * wtil_s[2*l]       + xv.y * wtil_s[2*l+1];
      float s1 = xv.x * wtil_s[D+2*l]     + xv.y * wtil_s[D+2*l+1];
      float s2 = xv.x * wtil_s[2*D+2*l]   + xv.y * wtil_s[2*D+2*l+1];
      float s3 = xv.x * wtil_s[3*D+2*l]   + xv.y * wtil_s[3*D+2*l+1];
      float d0 = xv.x * wtil_d[2*l]       + xv.y * wtil_d[2*l+1];
      float d1 = xv.x * wtil_d[D+2*l]     + xv.y * wtil_d[D+2*l+1];
      float d2 = xv.x * wtil_d[2*D+2*l]   + xv.y * wtil_d[2*D+2*l+1];
      float d3 = xv.x * wtil_d[3*D+2*l]   + xv.y * wtil_d[3*D+2*l+1];
      #pragma unroll
      for (int off = 32; off; off >>= 1) {
        s0 += __shfl_xor(s0, off); s1 += __shfl_xor(s1, off);
        s2 += __shfl_xor(s2, off); s3 += __shfl_xor(s3, off);
        d0 += __shfl_xor(d0, off); d1 += __shfl_xor(d1, off);
        d2 += __shfl_xor(d2, off); d3 += __shfl_xor(d3, off);
      }
      if (l == 0) {
        ((float4*)a_s)[n] = make_float4(s0, s1, s2, s3);
        ((float4*)a_d)[n] = make_float4(d0, d1, d2, d3);
      }
    }
  }
  // ---- phase 1b: edge deg count ----
  for (int vb = blockIdx.x; vb < NBE; vb += nblk) {
    int e = vb * 256 + t;
    if (e < E + N) {
      int dst = (e < E) ? ei[E + e] : (e - E);
      atomicAdd(&deg[dst], 1);
    }
  }
  grid.sync();

  // ---- phase 2: per-block reduce -> bsum ----
  for (int vb = blockIdx.x; vb < nb; vb += nblk) {
    int i = vb * 256 + t;
    sA[t] = (i < N) ? deg[i] : 0;
    __syncthreads();
    for (int off = 128; off; off >>= 1) {
      if (t < off) sA[t] += sA[t + off];
      __syncthreads();
    }
    if (t == 0) bsum[vb] = sA[0];
    __syncthreads();
  }
  grid.sync();

  // ---- phase 3: block scan + base -> row_ptr/cursor/dinv ----
  for (int vb = blockIdx.x; vb < nb; vb += nblk) {
    const int i = vb * 256 + t;
    const int v = (i < N) ? deg[i] : 0;
    sA[t] = v;
    sB[t] = (t < vb && t < nb) ? bsum[t] : 0;
    __syncthreads();
    for (int off = 1; off < 256; off <<= 1) {
      int xv = (t >= off) ? sA[t - off] : 0;
      __syncthreads();
      sA[t] += xv;
      __syncthreads();
    }
    for (int off = 128; off; off >>= 1) {
      if (t < off) sB[t] += sB[t + off];
      __syncthreads();
    }
    const int base = sB[0];
    if (i < N) {
      int excl = base + sA[t] - v;
      row_ptr[i] = excl;
      cursor[i] = excl;
      dinv[i] = rsqrtf((float)v);
    }
    if (i == 0) row_ptr[N] = Et;
    __syncthreads();
  }
  grid.sync();

  // ---- phase 4: fill ----
  for (int vb = blockIdx.x; vb < NBE; vb += nblk) {
    int e = vb * 256 + t;
    if (e < E + N) {
      int src, dst;
      if (e < E) { src = ei[e]; dst = ei[E + e]; }
      else       { src = e - E; dst = src; }
      int pos = atomicAdd(&cursor[dst], 1);
      col_src[pos] = src;
    }
  }
  grid.sync();

  // ---- phase 5: aggregation (8-edge unroll) ----
  for (int vb = blockIdx.x; vb < NG; vb += nblk) {
    const int hw = t >> 5, lh = t & 31;
    const int n = vb * 8 + hw;
    if (n < N) {
      const int start = row_ptr[n], end = row_ptr[n + 1];
      const float4 adn = ((const float4*)a_d)[n];
      float den0 = 0.f, den1 = 0.f, den2 = 0.f, den3 = 0.f;
      float ug[4][4] = {};
      float vg[4] = {};
      for (int base = start; base < end; base += 32) {
        const int cnt = min(32, end - base);
        if (lh < cnt) {
          int s = col_src[base + lh];
          float4 as4 = ((const float4*)a_s)[s];
          float e0 = as4.x + adn.x; e0 = (e0 >= 0.f) ? e0 : NEG_SLOPE * e0;
          float e1 = as4.y + adn.y; e1 = (e1 >= 0.f) ? e1 : NEG_SLOPE * e1;
          float e2 = as4.z + adn.z; e2 = (e2 >= 0.f) ? e2 : NEG_SLOPE * e2;
          float e3 = as4.w + adn.w; e3 = (e3 >= 0.f) ? e3 : NEG_SLOPE * e3;
          float x0 = __expf(e0), x1 = __expf(e1), x2 = __expf(e2), x3 = __expf(e3);
          den0 += x0; den1 += x1; den2 += x2; den3 += x3;
          sh_al[hw][lh] = make_float4(x0, x1, x2, x3);
          sh_src[hw][lh] = s;
          sh_cf[hw][lh] = dinv[s];
        }
        if (lh < 7) {
          sh_al[hw][cnt + lh] = make_float4(0.f, 0.f, 0.f, 0.f);
          sh_src[hw][cnt + lh] = 0;
          sh_cf[hw][cnt + lh] = 0.f;
        }
        for (int j = 0; j < cnt; j += 8) {
          ushort4 xv[8];
          float4 al[8];
          float cf[8];
          #pragma unroll
          for (int u = 0; u < 8; ++u) {
            int s = sh_src[hw][j + u];
            xv[u] = *(const ushort4*)(xb + ((size_t)s << 7) + (lh << 2));
          }
          #pragma unroll
          for (int u = 0; u < 8; ++u) {
            al[u] = sh_al[hw][j + u];
            cf[u] = sh_cf[hw][j + u];
          }
          #pragma unroll
          for (int u = 0; u < 8; ++u) ACC_EDGE(al[u], cf[u], xv[u]);
        }
      }
      #pragma unroll
      for (int off = 16; off; off >>= 1) {
        den0 += __shfl_xor(den0, off); den1 += __shfl_xor(den1, off);
        den2 += __shfl_xor(den2, off); den3 += __shfl_xor(den3, off);
      }
      const float r[4] = {1.f / den0, 1.f / den1, 1.f / den2, 1.f / den3};
      const float dn = dinv[n];
      unsigned short* uvp = UV + (size_t)n * 640;
      #pragma unroll
      for (int h = 0; h < 4; ++h) {
        ushort4 u;
        u.x = f2bf(ug[h][0] * r[h]); u.y = f2bf(ug[h][1] * r[h]);
        u.z = f2bf(ug[h][2] * r[h]); u.w = f2bf(ug[h][3] * r[h]);
        *(ushort4*)(uvp + h * 128 + 4 * lh) = u;
      }
      ushort4 v4;
      v4.x = f2bf(vg[0] * dn); v4.y = f2bf(vg[1] * dn);
      v4.z = f2bf(vg[2] * dn); v4.w = f2bf(vg[3] * dn);
      *(ushort4*)(uvp + 512 + 4 * lh) = v4;
    }
  }
}

// ================== fallback separate kernels (used if coop launch fails) ========
__global__ __launch_bounds__(256) void k_xb_deg(
    const float* __restrict__ x,
    const float* __restrict__ wtil_s, const float* __restrict__ wtil_d,
    unsigned short* __restrict__ xb, float* __restrict__ a_s, float* __restrict__ a_d,
    const int* __restrict__ ei, int* __restrict__ deg,
    int N, int E, int NBN)
{
  if ((int)blockIdx.x >= NBN) {
    int e = (blockIdx.x - NBN) * 256 + threadIdx.x;
    if (e < E + N) {
      int dst = (e < E) ? ei[E + e] : (e - E);
      atomicAdd(&deg[dst], 1);
    }
    return;
  }
  const int w = threadIdx.x >> 6, l = threadIdx.x & 63;
  const int n = blockIdx.x * 4 + w;
  if (n >= N) return;
  float2 xv = ((const float2*)(x + (size_t)n * D))[l];
  ushort2 p; p.x = f2bf(xv.x); p.y = f2bf(xv.y);
  *(ushort2*)(xb + (size_t)n * D + 2 * l) = p;
  float s0 = xv.x * wtil_s[2*l]       + xv.y * wtil_s[2*l+1];
  float s1 = xv.x * wtil_s[D+2*l]     + xv.y * wtil_s[D+2*l+1];
  float s2 = xv.x * wtil_s[2*D+2*l]   + xv.y * wtil_s[2*D+2*l+1];
  float s3 = xv.x * wtil_s[3*D+2*l]   + xv.y * wtil_s[3*D+2*l+1];
  float d0 = xv.x * wtil_d[2*l]       + xv.y * wtil_d[2*l+1];
  float d1 = xv.x * wtil_d[D+2*l]     + xv.y * wtil_d[D+2*l+1];
  float d2 = xv.x * wtil_d[2*D+2*l]   + xv.y * wtil_d[2*D+2*l+1];
  float d3 = xv.x * wtil_d[3*D+2*l]   + xv.y * wtil_d[3*D+2*l+1];
  #pragma unroll
  for (int off = 32; off; off >>= 1) {
    s0 += __shfl_xor(s0, off); s1 += __shfl_xor(s1, off);
    s2 += __shfl_xor(s2, off); s3 += __shfl_xor(s3, off);
    d0 += __shfl_xor(d0, off); d1 += __shfl_xor(d1, off);
    d2 += __shfl_xor(d2, off); d3 += __shfl_xor(d3, off);
  }
  if (l == 0) {
    ((float4*)a_s)[n] = make_float4(s0, s1, s2, s3);
    ((float4*)a_d)[n] = make_float4(d0, d1, d2, d3);
  }
}

__global__ void k_scan1(const int* __restrict__ deg, int N, int* __restrict__ bsum)
{
  __shared__ int s[256];
  int t = threadIdx.x;
  int i = blockIdx.x * 256 + t;
  s[t] = (i < N) ? deg[i] : 0;
  __syncthreads();
  for (int off = 128; off; off >>= 1) {
    if (t < off) s[t] += s[t + off];
    __syncthreads();
  }
  if (t == 0) bsum[blockIdx.x] = s[0];
}

__global__ void k_scan3(const int* __restrict__ deg, const int* __restrict__ bsum,
                        int nb, int N, int Et, int* __restrict__ row_ptr,
                        int* __restrict__ cursor, float* __restrict__ dinv)
{
  __shared__ int s[256];
  __shared__ int r[256];
  const int t = threadIdx.x, b = blockIdx.x;
  const int i = b * 256 + t;
  const int v = (i < N) ? deg[i] : 0;
  s[t] = v;
  r[t] = (t < b && t < nb) ? bsum[t] : 0;
  __syncthreads();
  for (int off = 1; off < 256; off <<= 1) {
    int xv = (t >= off) ? s[t - off] : 0;
    __syncthreads();
    s[t] += xv;
    __syncthreads();
  }
  for (int off = 128; off; off >>= 1) {
    if (t < off) r[t] += r[t + off];
    __syncthreads();
  }
  const int base = r[0];
  if (i < N) {
    int excl = base + s[t] - v;
    row_ptr[i] = excl;
    cursor[i] = excl;
    dinv[i] = rsqrtf((float)v);
  }
  if (i == 0) row_ptr[N] = Et;
}

__global__ void k_fill(const int* __restrict__ ei, int E, int N,
                       int* __restrict__ cursor, int* __restrict__ col_src)
{
  int e = blockIdx.x * blockDim.x + threadIdx.x;
  if (e >= E + N) return;
  int src, dst;
  if (e < E) { src = ei[e]; dst = ei[E + e]; }
  else       { src = e - E; dst = src; }
  int pos = atomicAdd(&cursor[dst], 1);
  col_src[pos] = src;
}

__global__ __launch_bounds__(256) void k_agg2(
    const unsigned short* __restrict__ xb,
    const float* __restrict__ a_s, const float* __restrict__ a_d,
    const int* __restrict__ row_ptr, const int* __restrict__ col_src,
    const float* __restrict__ dinv,
    unsigned short* __restrict__ UV, int N)
{
  __shared__ float4 sh_al[8][40];
  __shared__ int    sh_src[8][40];
  __shared__ float  sh_cf[8][40];
  const int hw = threadIdx.x >> 5, lh = threadIdx.x & 31;
  const int n = blockIdx.x * 8 + hw;
  if (n >= N) return;
  const int start = row_ptr[n], end = row_ptr[n + 1];
  const float4 adn = ((const float4*)a_d)[n];

  float den0 = 0.f, den1 = 0.f, den2 = 0.f, den3 = 0.f;
  float ug[4][4] = {};
  float vg[4] = {};

  for (int base = start; base < end; base += 32) {
    const int cnt = min(32, end - base);
    if (lh < cnt) {
      int s = col_src[base + lh];
      float4 as4 = ((const float4*)a_s)[s];
      float e0 = as4.x + adn.x; e0 = (e0 >= 0.f) ? e0 : NEG_SLOPE * e0;
      float e1 = as4.y + adn.y; e1 = (e1 >= 0.f) ? e1 : NEG_SLOPE * e1;
      float e2 = as4.z + adn.z; e2 = (e2 >= 0.f) ? e2 : NEG_SLOPE * e2;
      float e3 = as4.w + adn.w; e3 = (e3 >= 0.f) ? e3 : NEG_SLOPE * e3;
      float x0 = __expf(e0), x1 = __expf(e1), x2 = __expf(e2), x3 = __expf(e3);
      den0 += x0; den1 += x1; den2 += x2; den3 += x3;
      sh_al[hw][lh] = make_float4(x0, x1, x2, x3);
      sh_src[hw][lh] = s;
      sh_cf[hw][lh] = dinv[s];
    }
    if (lh < 7) {
      sh_al[hw][cnt + lh] = make_float4(0.f, 0.f, 0.f, 0.f);
      sh_src[hw][cnt + lh] = 0;
      sh_cf[hw][cnt + lh] = 0.f;
    }
    for (int j = 0; j < cnt; j += 8) {
      ushort4 xv[8];
      float4 al[8];
      float cf[8];
      #pragma unroll
      for (int u = 0; u < 8; ++u) {
        int s = sh_src[hw][j + u];
        xv[u] = *(const ushort4*)(xb + ((size_t)s << 7) + (lh << 2));
      }
      #pragma unroll
      for (int u = 0; u < 8; ++u) {
        al[u] = sh_al[hw][j + u];
        cf[u] = sh_cf[hw][j + u];
      }
      #pragma unroll
      for (int u = 0; u < 8; ++u) ACC_EDGE(al[u], cf[u], xv[u]);
    }
  }

  #pragma unroll
  for (int off = 16; off; off >>= 1) {
    den0 += __shfl_xor(den0, off); den1 += __shfl_xor(den1, off);
    den2 += __shfl_xor(den2, off); den3 += __shfl_xor(den3, off);
  }
  const float r[4] = {1.f / den0, 1.f / den1, 1.f / den2, 1.f / den3};
  const float dn = dinv[n];
  unsigned short* uvp = UV + (size_t)n * 640;
  #pragma unroll
  for (int h = 0; h < 4; ++h) {
    ushort4 u;
    u.x = f2bf(ug[h][0] * r[h]); u.y = f2bf(ug[h][1] * r[h]);
    u.z = f2bf(ug[h][2] * r[h]); u.w = f2bf(ug[h][3] * r[h]);
    *(ushort4*)(uvp + h * 128 + 4 * lh) = u;
  }
  ushort4 v4;
  v4.x = f2bf(vg[0] * dn); v4.y = f2bf(vg[1] * dn);
  v4.z = f2bf(vg[2] * dn); v4.w = f2bf(vg[3] * dn);
  *(ushort4*)(uvp + 512 + 4 * lh) = v4;
}

// ---------------- fused MFMA GEMM + gate + LayerNorm (BM=64) --------------------
__global__ __launch_bounds__(256) void k_gemm3(
    const unsigned short* __restrict__ UV,
    const unsigned short* __restrict__ Wt2g, const unsigned short* __restrict__ Wt2c,
    const float* __restrict__ b_gat, const float* __restrict__ b_gcn,
    const float* __restrict__ W_gate, const float* __restrict__ b_gate,
    const float* __restrict__ gamma, const float* __restrict__ beta,
    float* __restrict__ out, int N)
{
  __shared__ unsigned short As[64 * 128];   // 16 KB, kb ^= row&7
  __shared__ unsigned short Bs[128 * 128];  // 32 KB, kb ^= col&7
  __shared__ float ec[8][128];
  const int t = threadIdx.x;
  const int m0 = blockIdx.x * 64;

  {
    int idx = t * 4;
    #pragma unroll
    for (int i = 0; i < 4; ++i) {
      int arr = (idx + i) >> 7, c = (idx + i) & 127;
      float v;
      switch (arr) {
        case 0: v = b_gat[c]; break;
        case 1: v = b_gcn[c]; break;
        case 2: v = W_gate[2 * c]; break;
        case 3: v = W_gate[2 * c + 1]; break;
        case 4: v = W_gate[256 + 2 * c]; break;
        case 5: v = W_gate[256 + 2 * c + 1]; break;
        case 6: v = gamma[c]; break;
        default: v = beta[c]; break;
      }
      ec[arr][c] = v;
    }
  }

  const int w = t >> 6, l = t & 63;
  const int lrow = l & 15, lk = l >> 4;
  const int arow = w * 16 + lrow;

  f32x4 accg[8], accc[8];
  #pragma unroll
  for (int n = 0; n < 8; ++n) {
    accg[n] = (f32x4){0.f, 0.f, 0.f, 0.f};
    accc[n] = (f32x4){0.f, 0.f, 0.f, 0.f};
  }

  for (int kc = 0; kc < 5; ++kc) {
    const int abase = (kc < 4) ? kc * 128 : 512;
    __syncthreads();
    #pragma unroll
    for (int i = 0; i < 4; ++i) {
      int g = i * 256 + t;
      int row = g >> 4, kb = g & 15;
      int gr = m0 + row;
      uint4 v = make_uint4(0u, 0u, 0u, 0u);
      if (gr < N) v = *(const uint4*)(UV + (size_t)gr * 640 + abase + kb * 8);
      *(uint4*)&As[row * 128 + ((kb ^ (row & 7)) << 3)] = v;
    }
    #pragma unroll
    for (int i = 0; i < 8; ++i) {
      int g = i * 256 + t;
      int col = g >> 4, kb = g & 15;
      uint4 v = (kc < 4)
        ? *(const uint4*)(Wt2g + (size_t)col * 512 + kc * 128 + kb * 8)
        : *(const uint4*)(Wt2c + (size_t)col * 128 + kb * 8);
      *(uint4*)&Bs[col * 128 + ((kb ^ (col & 7)) << 3)] = v;
    }
    __syncthreads();
    f32x4* acc = (kc < 4) ? accg : accc;
    #pragma unroll
    for (int ks = 0; ks < 4; ++ks) {
      int kb = ks * 4 + lk;
      bf16x8 a = *(const bf16x8*)&As[arow * 128 + ((kb ^ (arow & 7)) << 3)];
      #pragma unroll
      for (int n = 0; n < 8; ++n) {
        int col = n * 16 + lrow;
        bf16x8 b = *(const bf16x8*)&Bs[col * 128 + ((kb ^ (col & 7)) << 3)];
        acc[n] = __builtin_amdgcn_mfma_f32_16x16x32_bf16(a, b, acc[n], 0, 0, 0);
      }
    }
  }

  const float bg0 = b_gate[0], bg1 = b_gate[1];
  #pragma unroll
  for (int j = 0; j < 4; ++j) {
    const int r = m0 + w * 16 + lk * 4 + j;
    float ga[8], gc[8];
    float z0 = 0.f, z1 = 0.f;
    #pragma unroll
    for (int n = 0; n < 8; ++n) {
      int c = n * 16 + lrow;
      ga[n] = accg[n][j] * 0.25f + ec[0][c];
      gc[n] = accc[n][j] + ec[1][c];
      z0 += ga[n] * ec[2][c] + gc[n] * ec[4][c];
      z1 += ga[n] * ec[3][c] + gc[n] * ec[5][c];
    }
    #pragma unroll
    for (int off = 8; off; off >>= 1) { z0 += __shfl_xor(z0, off); z1 += __shfl_xor(z1, off); }
    z0 += bg0; z1 += bg1;
    float mz = fmaxf(z0, z1);
    float e0 = __expf(z0 - mz), e1 = __expf(z1 - mz);
    float inv = 1.f / (e0 + e1);
    float w0 = e0 * inv, w1 = e1 * inv;
    float h[8], ss = 0.f;
    #pragma unroll
    for (int n = 0; n < 8; ++n) { h[n] = (1.f + w0) * ga[n] + w1 * gc[n]; ss += h[n]; }
    #pragma unroll
    for (int off = 8; off; off >>= 1) ss += __shfl_xor(ss, off);
    float mu = ss * (1.f / 128.f);
    float vs = 0.f;
    #pragma unroll
    for (int n = 0; n < 8; ++n) { h[n] -= mu; vs += h[n] * h[n]; }
    #pragma unroll
    for (int off = 8; off; off >>= 1) vs += __shfl_xor(vs, off);
    float rstd = rsqrtf(vs * (1.f / 128.f) + LN_EPS);
    if (r < N) {
      #pragma unroll
      for (int n = 0; n < 8; ++n) {
        int c = n * 16 + lrow;
        out[(size_t)r * 128 + c] = h[n] * rstd * ec[6][c] + ec[7][c];
      }
    }
  }
}

extern "C" void kernel_launch(void* const* d_in, const int* in_sizes, int n_in,
                              void* d_out, int out_size, void* d_ws, size_t ws_size,
                              hipStream_t stream)
{
  const float* x       = (const float*)d_in[0];
  const int*   ei      = (const int*)d_in[1];
  const float* Wgat    = (const float*)d_in[2];
  const float* att_src = (const float*)d_in[3];
  const float* att_dst = (const float*)d_in[4];
  const float* b_gat   = (const float*)d_in[5];
  const float* Wgcn    = (const float*)d_in[6];
  const float* b_gcn   = (const float*)d_in[7];
  const float* W_gate  = (const float*)d_in[8];
  const float* b_gate  = (const float*)d_in[9];
  const float* gamma   = (const float*)d_in[10];
  const float* beta    = (const float*)d_in[11];
  float* out = (float*)d_out;

  int N  = in_sizes[0] / D;   // 30000
  int E  = in_sizes[1] / 2;   // 480000
  int Et = E + N;

  char* p = (char*)d_ws;
  unsigned short* xb   = (unsigned short*)p; p += (size_t)N * D * 2;
  unsigned short* UV   = (unsigned short*)p; p += (size_t)N * 640 * 2;
  unsigned short* Wt2g = (unsigned short*)p; p += (size_t)128 * 512 * 2;
  unsigned short* Wt2c = (unsigned short*)p; p += (size_t)128 * 128 * 2;
  float* wtil_s  = (float*)p; p += 512 * 4;
  float* wtil_d  = (float*)p; p += 512 * 4;
  float* a_s     = (float*)p; p += (size_t)N * NH * 4;
  float* a_d     = (float*)p; p += (size_t)N * NH * 4;
  float* dinv    = (float*)p; p += (size_t)N * 4;
  int* deg       = (int*)p;   p += (size_t)N * 4;
  int* row_ptr   = (int*)p;   p += (size_t)(N + 1) * 4;
  int* cursor    = (int*)p;   p += (size_t)N * 4;
  int* col_src   = (int*)p;   p += (size_t)Et * 4;
  int* bsum      = (int*)p;   p += 1024;

  int NBN = (N + 3) / 4;
  int NBE = (Et + 255) / 256;
  int nzb = (N + 127) / 128;
  int nb  = (N + 255) / 256;   // 118
  int NG  = (N + 7) / 8;

  k_prep<<<264 + nzb, 128, 0, stream>>>(
      Wgat, Wgcn, att_src, att_dst, Wt2g, Wt2c, wtil_s, wtil_d, deg, N);

  // cooperative mega kernel (phases 1-5); fall back to separate kernels on error
  int maxB = 0;
  hipError_t oerr = hipOccupancyMaxActiveBlocksPerMultiprocessor(
      &maxB, (const void*)k_mega, 256, 0);
  int grid = (oerr == hipSuccess && maxB > 0) ? maxB * 256 : 512;
  if (grid > 2048) grid = 2048;
  int maxwork = NBE;
  if (NBN > maxwork) maxwork = NBN;
  if (NG > maxwork) maxwork = NG;
  if (grid > maxwork) grid = maxwork;

  void* args[] = {
    (void*)&x, (void*)&wtil_s, (void*)&wtil_d, (void*)&xb, (void*)&a_s, (void*)&a_d,
    (void*)&ei, (void*)&deg, (void*)&bsum, (void*)&row_ptr, (void*)&cursor,
    (void*)&dinv, (void*)&col_src, (void*)&UV,
    (void*)&N, (void*)&E, (void*)&Et, (void*)&NBN, (void*)&NBE, (void*)&nb, (void*)&NG
  };
  hipError_t lerr = hipLaunchCooperativeKernel(
      (void*)k_mega, dim3(grid), dim3(256), args, 0, stream);
  if (lerr != hipSuccess) {
    k_xb_deg<<<NBN + NBE, 256, 0, stream>>>(x, wtil_s, wtil_d, xb, a_s, a_d,
                                             ei, deg, N, E, NBN);
    k_scan1<<<nb, 256, 0, stream>>>(deg, N, bsum);
    k_scan3<<<nb, 256, 0, stream>>>(deg, bsum, nb, N, Et, row_ptr, cursor, dinv);
    k_fill<<<NBE, 256, 0, stream>>>(ei, E, N, cursor, col_src);
    k_agg2<<<NG, 256, 0, stream>>>(xb, a_s, a_d, row_ptr, col_src, dinv, UV, N);
  }

  k_gemm3<<<(N + 63) / 64, 256, 0, stream>>>(UV, Wt2g, Wt2c, b_gat, b_gcn,
                                              W_gate, b_gate, gamma, beta, out, N);
  (void)n_in; (void)out_size; (void)ws_size;
}

// Round 16
// 126.528 us; speedup vs baseline: 2.9549x; 2.9549x over previous
//
#include <hip/hip_runtime.h>
#include <hip/hip_bf16.h>

#define D 128
#define NH 4
#define NEG_SLOPE 0.2f
#define LN_EPS 1e-5f

typedef __attribute__((ext_vector_type(4))) float f32x4;
typedef __attribute__((ext_vector_type(8))) short bf16x8;

__device__ __forceinline__ float bf2f(unsigned short u) {
  union { unsigned int i; float f; } c; c.i = ((unsigned int)u) << 16; return c.f;
}
__device__ __forceinline__ unsigned short f2bf(float f) {
  union { float f; unsigned int i; } c; c.f = f;
  unsigned int r = c.i + 0x7FFFu + ((c.i >> 16) & 1u);  // RNE
  return (unsigned short)(r >> 16);
}

// ---------------- weight prep + deg zeroing -------------------------------------
// blocks 0..127: Wt2g; 128..255: Wt2c; 256..263: wtil; 264..: deg[...]=0
__global__ __launch_bounds__(128) void k_prep(
    const float* __restrict__ Wgat, const float* __restrict__ Wgcn,
    const float* __restrict__ att_src, const float* __restrict__ att_dst,
    unsigned short* __restrict__ Wt2g, unsigned short* __restrict__ Wt2c,
    float* __restrict__ wtil_s, float* __restrict__ wtil_d,
    int* __restrict__ deg, int N)
{
  int c = blockIdx.x, t = threadIdx.x;
  if (c < 128) {
    #pragma unroll
    for (int i = 0; i < 4; ++i) {
      int k = t + i * 128;
      int h = k >> 7, kk = k & 127;
      Wt2g[c * 512 + k] = f2bf(Wgat[((size_t)h * D + kk) * D + c]);
    }
  } else if (c < 256) {
    int cc = c - 128;
    Wt2c[cc * 128 + t] = f2bf(Wgcn[(size_t)t * D + cc]);
  } else if (c < 264) {
    int b2 = c - 256;
    int h = b2 >> 1, which = b2 & 1;
    const float* av = (which ? att_dst : att_src) + h * D;
    const float* Wrow = Wgat + ((size_t)h * D + t) * D;
    float s = 0.f;
    for (int f = 0; f < D; ++f) s += Wrow[f] * av[f];
    (which ? wtil_d : wtil_s)[h * D + t] = s;
  } else {
    int i = (c - 264) * 128 + t;
    if (i < N) deg[i] = 0;
  }
}

// ---------------- fused: x->bf16 + attention dots  ||  edge deg count -----------
__global__ __launch_bounds__(256) void k_xb_deg(
    const float* __restrict__ x,
    const float* __restrict__ wtil_s, const float* __restrict__ wtil_d,
    unsigned short* __restrict__ xb, float* __restrict__ a_s, float* __restrict__ a_d,
    const int* __restrict__ ei, int* __restrict__ deg,
    int N, int E, int NBN)
{
  if ((int)blockIdx.x >= NBN) {
    int e = (blockIdx.x - NBN) * 256 + threadIdx.x;
    if (e < E + N) {
      int dst = (e < E) ? ei[E + e] : (e - E);
      atomicAdd(&deg[dst], 1);
    }
    return;
  }
  const int w = threadIdx.x >> 6, l = threadIdx.x & 63;
  const int n = blockIdx.x * 4 + w;
  if (n >= N) return;
  float2 xv = ((const float2*)(x + (size_t)n * D))[l];
  ushort2 p; p.x = f2bf(xv.x); p.y = f2bf(xv.y);
  *(ushort2*)(xb + (size_t)n * D + 2 * l) = p;
  float s0 = xv.x * wtil_s[2*l]       + xv.y * wtil_s[2*l+1];
  float s1 = xv.x * wtil_s[D+2*l]     + xv.y * wtil_s[D+2*l+1];
  float s2 = xv.x * wtil_s[2*D+2*l]   + xv.y * wtil_s[2*D+2*l+1];
  float s3 = xv.x * wtil_s[3*D+2*l]   + xv.y * wtil_s[3*D+2*l+1];
  float d0 = xv.x * wtil_d[2*l]       + xv.y * wtil_d[2*l+1];
  float d1 = xv.x * wtil_d[D+2*l]     + xv.y * wtil_d[D+2*l+1];
  float d2 = xv.x * wtil_d[2*D+2*l]   + xv.y * wtil_d[2*D+2*l+1];
  float d3 = xv.x * wtil_d[3*D+2*l]   + xv.y * wtil_d[3*D+2*l+1];
  #pragma unroll
  for (int off = 32; off; off >>= 1) {
    s0 += __shfl_xor(s0, off); s1 += __shfl_xor(s1, off);
    s2 += __shfl_xor(s2, off); s3 += __shfl_xor(s3, off);
    d0 += __shfl_xor(d0, off); d1 += __shfl_xor(d1, off);
    d2 += __shfl_xor(d2, off); d3 += __shfl_xor(d3, off);
  }
  if (l == 0) {
    ((float4*)a_s)[n] = make_float4(s0, s1, s2, s3);
    ((float4*)a_d)[n] = make_float4(d0, d1, d2, d3);
  }
}

// ---------------- CSR scan (2 launches) -----------------------------------------
__global__ void k_scan1(const int* __restrict__ deg, int N, int* __restrict__ bsum)
{
  __shared__ int s[256];
  int t = threadIdx.x;
  int i = blockIdx.x * 256 + t;
  s[t] = (i < N) ? deg[i] : 0;
  __syncthreads();
  for (int off = 128; off; off >>= 1) {
    if (t < off) s[t] += s[t + off];
    __syncthreads();
  }
  if (t == 0) bsum[blockIdx.x] = s[0];
}

// block b: internal inclusive scan of its 256 degs + base = sum(bsum[0..b-1])
__global__ void k_scan3(const int* __restrict__ deg, const int* __restrict__ bsum,
                        int nb, int N, int Et, int* __restrict__ row_ptr,
                        int* __restrict__ cursor, float* __restrict__ dinv)
{
  __shared__ int s[256];
  __shared__ int r[256];
  const int t = threadIdx.x, b = blockIdx.x;
  const int i = b * 256 + t;
  const int v = (i < N) ? deg[i] : 0;
  s[t] = v;
  r[t] = (t < b && t < nb) ? bsum[t] : 0;
  __syncthreads();
  for (int off = 1; off < 256; off <<= 1) {
    int xv = (t >= off) ? s[t - off] : 0;
    __syncthreads();
    s[t] += xv;
    __syncthreads();
  }
  for (int off = 128; off; off >>= 1) {
    if (t < off) r[t] += r[t + off];
    __syncthreads();
  }
  const int base = r[0];
  if (i < N) {
    int excl = base + s[t] - v;
    row_ptr[i] = excl;
    cursor[i] = excl;
    dinv[i] = rsqrtf((float)v);    // deg >= 1 (self-loop)
  }
  if (i == 0) row_ptr[N] = Et;
}

__global__ void k_fill(const int* __restrict__ ei, int E, int N,
                       int* __restrict__ cursor, int* __restrict__ col_src)
{
  int e = blockIdx.x * blockDim.x + threadIdx.x;
  if (e >= E + N) return;
  int src, dst;
  if (e < E) { src = ei[e]; dst = ei[E + e]; }
  else       { src = e - E; dst = src; }
  int pos = atomicAdd(&cursor[dst], 1);
  col_src[pos] = src;
}

// ---------------- x-domain aggregation (8-edge unroll) --------------------------
#define ACC_EDGE(AL, CF, XV) do {                                        \
    float fa_[4] = {bf2f(XV.x), bf2f(XV.y), bf2f(XV.z), bf2f(XV.w)};     \
    float aa_[4] = {AL.x, AL.y, AL.z, AL.w};                             \
    _Pragma("unroll") for (int h_ = 0; h_ < 4; ++h_)                     \
      _Pragma("unroll") for (int d_ = 0; d_ < 4; ++d_)                   \
        ug[h_][d_] += aa_[h_] * fa_[d_];                                 \
    _Pragma("unroll") for (int d_ = 0; d_ < 4; ++d_)                     \
      vg[d_] += (CF) * fa_[d_];                                          \
  } while (0)

__global__ __launch_bounds__(256) void k_agg2(
    const unsigned short* __restrict__ xb,
    const float* __restrict__ a_s, const float* __restrict__ a_d,
    const int* __restrict__ row_ptr, const int* __restrict__ col_src,
    const float* __restrict__ dinv,
    unsigned short* __restrict__ UV, int N)
{
  __shared__ float4 sh_al[8][40];
  __shared__ int    sh_src[8][40];
  __shared__ float  sh_cf[8][40];
  const int hw = threadIdx.x >> 5, lh = threadIdx.x & 31;
  const int n = blockIdx.x * 8 + hw;
  if (n >= N) return;
  const int start = row_ptr[n], end = row_ptr[n + 1];
  const float4 adn = ((const float4*)a_d)[n];

  float den0 = 0.f, den1 = 0.f, den2 = 0.f, den3 = 0.f;
  float ug[4][4] = {};
  float vg[4] = {};

  for (int base = start; base < end; base += 32) {
    const int cnt = min(32, end - base);
    if (lh < cnt) {
      int s = col_src[base + lh];
      float4 as4 = ((const float4*)a_s)[s];
      float e0 = as4.x + adn.x; e0 = (e0 >= 0.f) ? e0 : NEG_SLOPE * e0;
      float e1 = as4.y + adn.y; e1 = (e1 >= 0.f) ? e1 : NEG_SLOPE * e1;
      float e2 = as4.z + adn.z; e2 = (e2 >= 0.f) ? e2 : NEG_SLOPE * e2;
      float e3 = as4.w + adn.w; e3 = (e3 >= 0.f) ? e3 : NEG_SLOPE * e3;
      float x0 = __expf(e0), x1 = __expf(e1), x2 = __expf(e2), x3 = __expf(e3);
      den0 += x0; den1 += x1; den2 += x2; den3 += x3;
      sh_al[hw][lh] = make_float4(x0, x1, x2, x3);
      sh_src[hw][lh] = s;
      sh_cf[hw][lh] = dinv[s];
    }
    if (lh < 7) {   // 7 sentinels (zero contribution) so j..j+7 never branches
      sh_al[hw][cnt + lh] = make_float4(0.f, 0.f, 0.f, 0.f);
      sh_src[hw][cnt + lh] = 0;
      sh_cf[hw][cnt + lh] = 0.f;
    }
    for (int j = 0; j < cnt; j += 8) {
      ushort4 xv[8];
      float4 al[8];
      float cf[8];
      #pragma unroll
      for (int u = 0; u < 8; ++u) {
        int s = sh_src[hw][j + u];
        xv[u] = *(const ushort4*)(xb + ((size_t)s << 7) + (lh << 2));
      }
      #pragma unroll
      for (int u = 0; u < 8; ++u) {
        al[u] = sh_al[hw][j + u];
        cf[u] = sh_cf[hw][j + u];
      }
      #pragma unroll
      for (int u = 0; u < 8; ++u) ACC_EDGE(al[u], cf[u], xv[u]);
    }
  }

  #pragma unroll
  for (int off = 16; off; off >>= 1) {
    den0 += __shfl_xor(den0, off); den1 += __shfl_xor(den1, off);
    den2 += __shfl_xor(den2, off); den3 += __shfl_xor(den3, off);
  }
  const float r[4] = {1.f / den0, 1.f / den1, 1.f / den2, 1.f / den3};
  const float dn = dinv[n];
  unsigned short* uvp = UV + (size_t)n * 640;
  #pragma unroll
  for (int h = 0; h < 4; ++h) {
    ushort4 u;
    u.x = f2bf(ug[h][0] * r[h]); u.y = f2bf(ug[h][1] * r[h]);
    u.z = f2bf(ug[h][2] * r[h]); u.w = f2bf(ug[h][3] * r[h]);
    *(ushort4*)(uvp + h * 128 + 4 * lh) = u;
  }
  ushort4 v4;
  v4.x = f2bf(vg[0] * dn); v4.y = f2bf(vg[1] * dn);
  v4.z = f2bf(vg[2] * dn); v4.w = f2bf(vg[3] * dn);
  *(ushort4*)(uvp + 512 + 4 * lh) = v4;
}

// ---------------- fused MFMA GEMM + gate + LayerNorm (BM=64) --------------------
__global__ __launch_bounds__(256) void k_gemm3(
    const unsigned short* __restrict__ UV,
    const unsigned short* __restrict__ Wt2g, const unsigned short* __restrict__ Wt2c,
    const float* __restrict__ b_gat, const float* __restrict__ b_gcn,
    const float* __restrict__ W_gate, const float* __restrict__ b_gate,
    const float* __restrict__ gamma, const float* __restrict__ beta,
    float* __restrict__ out, int N)
{
  __shared__ unsigned short As[64 * 128];   // 16 KB, kb ^= row&7
  __shared__ unsigned short Bs[128 * 128];  // 32 KB, kb ^= col&7
  __shared__ float ec[8][128];
  const int t = threadIdx.x;
  const int m0 = blockIdx.x * 64;

  {
    int idx = t * 4;
    #pragma unroll
    for (int i = 0; i < 4; ++i) {
      int arr = (idx + i) >> 7, c = (idx + i) & 127;
      float v;
      switch (arr) {
        case 0: v = b_gat[c]; break;
        case 1: v = b_gcn[c]; break;
        case 2: v = W_gate[2 * c]; break;
        case 3: v = W_gate[2 * c + 1]; break;
        case 4: v = W_gate[256 + 2 * c]; break;
        case 5: v = W_gate[256 + 2 * c + 1]; break;
        case 6: v = gamma[c]; break;
        default: v = beta[c]; break;
      }
      ec[arr][c] = v;
    }
  }

  const int w = t >> 6, l = t & 63;
  const int lrow = l & 15, lk = l >> 4;
  const int arow = w * 16 + lrow;

  f32x4 accg[8], accc[8];
  #pragma unroll
  for (int n = 0; n < 8; ++n) {
    accg[n] = (f32x4){0.f, 0.f, 0.f, 0.f};
    accc[n] = (f32x4){0.f, 0.f, 0.f, 0.f};
  }

  for (int kc = 0; kc < 5; ++kc) {
    const int abase = (kc < 4) ? kc * 128 : 512;
    __syncthreads();
    #pragma unroll
    for (int i = 0; i < 4; ++i) {        // A: 64 rows x 16 kb = 1024 uint4
      int g = i * 256 + t;
      int row = g >> 4, kb = g & 15;
      int gr = m0 + row;
      uint4 v = make_uint4(0u, 0u, 0u, 0u);
      if (gr < N) v = *(const uint4*)(UV + (size_t)gr * 640 + abase + kb * 8);
      *(uint4*)&As[row * 128 + ((kb ^ (row & 7)) << 3)] = v;
    }
    #pragma unroll
    for (int i = 0; i < 8; ++i) {        // B: 128 cols x 16 kb = 2048 uint4
      int g = i * 256 + t;
      int col = g >> 4, kb = g & 15;
      uint4 v = (kc < 4)
        ? *(const uint4*)(Wt2g + (size_t)col * 512 + kc * 128 + kb * 8)
        : *(const uint4*)(Wt2c + (size_t)col * 128 + kb * 8);
      *(uint4*)&Bs[col * 128 + ((kb ^ (col & 7)) << 3)] = v;
    }
    __syncthreads();
    f32x4* acc = (kc < 4) ? accg : accc;
    #pragma unroll
    for (int ks = 0; ks < 4; ++ks) {
      int kb = ks * 4 + lk;
      bf16x8 a = *(const bf16x8*)&As[arow * 128 + ((kb ^ (arow & 7)) << 3)];
      #pragma unroll
      for (int n = 0; n < 8; ++n) {
        int col = n * 16 + lrow;
        bf16x8 b = *(const bf16x8*)&Bs[col * 128 + ((kb ^ (col & 7)) << 3)];
        acc[n] = __builtin_amdgcn_mfma_f32_16x16x32_bf16(a, b, acc[n], 0, 0, 0);
      }
    }
  }

  const float bg0 = b_gate[0], bg1 = b_gate[1];
  #pragma unroll
  for (int j = 0; j < 4; ++j) {
    const int r = m0 + w * 16 + lk * 4 + j;
    float ga[8], gc[8];
    float z0 = 0.f, z1 = 0.f;
    #pragma unroll
    for (int n = 0; n < 8; ++n) {
      int c = n * 16 + lrow;
      ga[n] = accg[n][j] * 0.25f + ec[0][c];
      gc[n] = accc[n][j] + ec[1][c];
      z0 += ga[n] * ec[2][c] + gc[n] * ec[4][c];
      z1 += ga[n] * ec[3][c] + gc[n] * ec[5][c];
    }
    #pragma unroll
    for (int off = 8; off; off >>= 1) { z0 += __shfl_xor(z0, off); z1 += __shfl_xor(z1, off); }
    z0 += bg0; z1 += bg1;
    float mz = fmaxf(z0, z1);
    float e0 = __expf(z0 - mz), e1 = __expf(z1 - mz);
    float inv = 1.f / (e0 + e1);
    float w0 = e0 * inv, w1 = e1 * inv;
    float h[8], ss = 0.f;
    #pragma unroll
    for (int n = 0; n < 8; ++n) { h[n] = (1.f + w0) * ga[n] + w1 * gc[n]; ss += h[n]; }
    #pragma unroll
    for (int off = 8; off; off >>= 1) ss += __shfl_xor(ss, off);
    float mu = ss * (1.f / 128.f);
    float vs = 0.f;
    #pragma unroll
    for (int n = 0; n < 8; ++n) { h[n] -= mu; vs += h[n] * h[n]; }
    #pragma unroll
    for (int off = 8; off; off >>= 1) vs += __shfl_xor(vs, off);
    float rstd = rsqrtf(vs * (1.f / 128.f) + LN_EPS);
    if (r < N) {
      #pragma unroll
      for (int n = 0; n < 8; ++n) {
        int c = n * 16 + lrow;
        out[(size_t)r * 128 + c] = h[n] * rstd * ec[6][c] + ec[7][c];
      }
    }
  }
}

extern "C" void kernel_launch(void* const* d_in, const int* in_sizes, int n_in,
                              void* d_out, int out_size, void* d_ws, size_t ws_size,
                              hipStream_t stream)
{
  const float* x       = (const float*)d_in[0];
  const int*   ei      = (const int*)d_in[1];
  const float* Wgat    = (const float*)d_in[2];
  const float* att_src = (const float*)d_in[3];
  const float* att_dst = (const float*)d_in[4];
  const float* b_gat   = (const float*)d_in[5];
  const float* Wgcn    = (const float*)d_in[6];
  const float* b_gcn   = (const float*)d_in[7];
  const float* W_gate  = (const float*)d_in[8];
  const float* b_gate  = (const float*)d_in[9];
  const float* gamma   = (const float*)d_in[10];
  const float* beta    = (const float*)d_in[11];
  float* out = (float*)d_out;

  const int N  = in_sizes[0] / D;   // 30000
  const int E  = in_sizes[1] / 2;   // 480000
  const int Et = E + N;

  char* p = (char*)d_ws;
  unsigned short* xb   = (unsigned short*)p; p += (size_t)N * D * 2;        // 7.7MB
  unsigned short* UV   = (unsigned short*)p; p += (size_t)N * 640 * 2;      // 38.4MB
  unsigned short* Wt2g = (unsigned short*)p; p += (size_t)128 * 512 * 2;
  unsigned short* Wt2c = (unsigned short*)p; p += (size_t)128 * 128 * 2;
  float* wtil_s  = (float*)p; p += 512 * 4;
  float* wtil_d  = (float*)p; p += 512 * 4;
  float* a_s     = (float*)p; p += (size_t)N * NH * 4;
  float* a_d     = (float*)p; p += (size_t)N * NH * 4;
  float* dinv    = (float*)p; p += (size_t)N * 4;
  int* deg       = (int*)p;   p += (size_t)N * 4;
  int* row_ptr   = (int*)p;   p += (size_t)(N + 1) * 4;
  int* cursor    = (int*)p;   p += (size_t)N * 4;
  int* col_src   = (int*)p;   p += (size_t)Et * 4;
  int* bsum      = (int*)p;   p += 1024;

  const int NBN = (N + 3) / 4;
  const int NBE = (Et + 255) / 256;
  const int nzb = (N + 127) / 128;
  const int nb  = (N + 255) / 256;   // 118

  k_prep<<<264 + nzb, 128, 0, stream>>>(
      Wgat, Wgcn, att_src, att_dst, Wt2g, Wt2c, wtil_s, wtil_d, deg, N);
  k_xb_deg<<<NBN + NBE, 256, 0, stream>>>(x, wtil_s, wtil_d, xb, a_s, a_d,
                                           ei, deg, N, E, NBN);
  k_scan1<<<nb, 256, 0, stream>>>(deg, N, bsum);
  k_scan3<<<nb, 256, 0, stream>>>(deg, bsum, nb, N, Et, row_ptr, cursor, dinv);
  k_fill<<<NBE, 256, 0, stream>>>(ei, E, N, cursor, col_src);
  k_agg2<<<(N + 7) / 8, 256, 0, stream>>>(xb, a_s, a_d, row_ptr, col_src, dinv, UV, N);
  k_gemm3<<<(N + 63) / 64, 256, 0, stream>>>(UV, Wt2g, Wt2c, b_gat, b_gcn,
                                              W_gate, b_gate, gamma, beta, out, N);
  (void)n_in; (void)out_size; (void)ws_size;
}